// Round 1
// baseline (640.761 us; speedup 1.0000x reference)
//
#include <hip/hip_runtime.h>
#include <hip/hip_bf16.h>

#define B_    2
#define N_    65536
#define M_    16384
#define K_    32
#define KP_   15
#define DIN_  64
#define DOUT_ 128
#define TM    16

__device__ inline float bf2f(unsigned short u) {
    union { unsigned int i; float f; } v; v.i = ((unsigned int)u) << 16; return v.f;
}
__device__ inline unsigned short f2bf(float f) {
    union { float f; unsigned int i; } v; v.f = f;
    unsigned int x = v.i;
    return (unsigned short)((x + 0x7fffu + ((x >> 16) & 1u)) >> 16);  // RNE
}

__device__ inline void unpack8(uint4 v, float* dst) {
    dst[0] = bf2f((unsigned short)(v.x & 0xffff)); dst[1] = bf2f((unsigned short)(v.x >> 16));
    dst[2] = bf2f((unsigned short)(v.y & 0xffff)); dst[3] = bf2f((unsigned short)(v.y >> 16));
    dst[4] = bf2f((unsigned short)(v.z & 0xffff)); dst[5] = bf2f((unsigned short)(v.z >> 16));
    dst[6] = bf2f((unsigned short)(v.w & 0xffff)); dst[7] = bf2f((unsigned short)(v.w >> 16));
}

// features (B, Din, N) f32  ->  featT (B, N+1, Din) bf16, row N zeroed (shadow)
__global__ __launch_bounds__(256) void transpose_feats(const float* __restrict__ feats,
                                                       unsigned short* __restrict__ featT) {
    const int b  = blockIdx.y;
    const int n0 = blockIdx.x * 64;
    const int t  = threadIdx.x;
    if (n0 >= N_) {                    // shadow row: zeros
        if (t < 32)
            ((unsigned int*)(featT + ((size_t)b * (N_ + 1) + N_) * DIN_))[t] = 0u;
        return;
    }
    __shared__ float tile[64][65];
    const int nl = t & 63, dl = t >> 6;
    #pragma unroll
    for (int i = 0; i < 16; ++i) {
        int d = dl + 4 * i;
        tile[d][nl] = feats[((size_t)b * DIN_ + d) * N_ + n0 + nl];
    }
    __syncthreads();
    const int d2 = (t & 31) * 2;
    const int nr = t >> 5;
    #pragma unroll
    for (int i = 0; i < 8; ++i) {
        int n = nr + 8 * i;
        unsigned short h0 = f2bf(tile[d2][n]);
        unsigned short h1 = f2bf(tile[d2 + 1][n]);
        unsigned int u = ((unsigned int)h1 << 16) | h0;
        ((unsigned int*)(featT + ((size_t)b * (N_ + 1) + n0 + n) * DIN_))[t & 31] = u;
    }
}

__global__ __launch_bounds__(256) void kpconv_fused(
    const float* __restrict__ points_xyz,
    const float* __restrict__ center_xyz,
    const int*   __restrict__ nidx,
    const float* __restrict__ kpts,
    const float* __restrict__ weights,
    const unsigned short* __restrict__ featT,
    float* __restrict__ out) {

    const int t  = threadIdx.x;
    const int b  = blockIdx.y;
    const int m0 = blockIdx.x * TM;

    __shared__ float wgt[TM][960];        // 61.4 KB  weighted[p*64+d] per local m
    __shared__ float wl[KP_][K_];         //  1.9 KB  kernel-correlation weights
    __shared__ float fbuf[2][K_][DIN_];   // 16.0 KB  gathered feats, double-buffered
    __shared__ float wts[64][DOUT_];      // 32.0 KB  weights chunk
    __shared__ float outl[TM][DOUT_];     //  8.0 KB  output staging

    const int gk = t >> 3, gp = t & 7;    // gather: thread -> (neighbor, 8-feat slice)
    const size_t ibase = ((size_t)b * M_ + m0) * K_;

    // ---- prologue: gather ml=0 directly into fbuf[0] ----
    {
        int n = nidx[ibase + gk];
        uint4 v = *(const uint4*)(featT + ((size_t)b * (N_ + 1) + n) * DIN_ + gp * 8);
        unpack8(v, &fbuf[0][gk][gp * 8]);
    }

    // ---- stage 1: per local m, compute w then weighted[ml][960] ----
    for (int ml = 0; ml < TM; ++ml) {
        const int cur = ml & 1;

        // (a) issue next gather into regs (latency hidden under compute below)
        uint4 v;
        const bool have = (ml + 1 < TM);
        if (have) {
            int n = nidx[ibase + (size_t)(ml + 1) * K_ + gk];
            v = *(const uint4*)(featT + ((size_t)b * (N_ + 1) + n) * DIN_ + gp * 8);
        }

        // (b) lanes 0..31 of wave 0: distances, m_dist, w[k][p]
        if (t < K_) {
            int n = nidx[ibase + (size_t)ml * K_ + t];
            float px, py, pz;
            if (n < N_) {
                const float* p = points_xyz + ((size_t)b * N_ + n) * 3;
                px = p[0]; py = p[1]; pz = p[2];
            } else {
                px = py = pz = -1000.0f;
            }
            const float* c = center_xyz + ((size_t)b * M_ + m0 + ml) * 3;
            float dx = px - c[0], dy = py - c[1], dz = pz - c[2];
            float dist = sqrtf(dx * dx + dy * dy + dz * dz);
            float md = dist;
            #pragma unroll
            for (int s = 16; s > 0; s >>= 1)
                md = fmaxf(md, __shfl_xor(md, s));
            float rsig = 1.0f / (md / 2.1f + 1e-5f);
            #pragma unroll
            for (int p = 0; p < KP_; ++p) {
                float ex = dx - kpts[p * 3 + 0] * md;
                float ey = dy - kpts[p * 3 + 1] * md;
                float ez = dz - kpts[p * 3 + 2] * md;
                float w = 1.0f - sqrtf(ex * ex + ey * ey + ez * ez) * rsig;
                wl[p][t] = w > 0.0f ? w : 0.0f;
            }
        }
        __syncthreads();

        // (c) weighted[ml][p][d] = sum_k w[k][p] * feats[k][d]; thread t<240 -> 4 outputs
        if (t < 240) {
            const int p = t >> 4, d0 = (t & 15) * 4;
            float a0 = 0.f, a1 = 0.f, a2 = 0.f, a3 = 0.f;
            #pragma unroll
            for (int k = 0; k < K_; ++k) {
                float wk = wl[p][k];
                const float* f = &fbuf[cur][k][d0];
                a0 += wk * f[0]; a1 += wk * f[1]; a2 += wk * f[2]; a3 += wk * f[3];
            }
            *(float4*)&wgt[ml][t * 4] = make_float4(a0, a1, a2, a3);
        }

        // (d) late LDS-write of the prefetched tile (vmcnt waits land here, post-compute)
        if (have)
            unpack8(v, &fbuf[cur ^ 1][gk][gp * 8]);
        __syncthreads();
    }

    // ---- stage 2: out[16][128] = wgt[16][960] x weights[960][128], LDS-tiled over pd ----
    const int ot = t & 31;        // 4 consecutive o per thread
    const int mlt = t >> 5;       // 2 consecutive ml per thread
    float acc[2][4] = {{0.f, 0.f, 0.f, 0.f}, {0.f, 0.f, 0.f, 0.f}};

    for (int c = 0; c < 15; ++c) {
        __syncthreads();          // protect wts from previous chunk's readers
        #pragma unroll
        for (int i = 0; i < 8; ++i) {
            int fi = i * 256 + t;
            ((float4*)wts)[fi] = ((const float4*)(weights + (size_t)c * 8192))[fi];
        }
        __syncthreads();
        #pragma unroll 4
        for (int pl = 0; pl < 64; pl += 2) {
            float4 wv0 = *(const float4*)&wts[pl][ot * 4];
            float4 wv1 = *(const float4*)&wts[pl + 1][ot * 4];
            int pd = c * 64 + pl;
            float2 g0 = *(const float2*)&wgt[mlt * 2][pd];
            float2 g1 = *(const float2*)&wgt[mlt * 2 + 1][pd];
            acc[0][0] += g0.x * wv0.x; acc[0][1] += g0.x * wv0.y;
            acc[0][2] += g0.x * wv0.z; acc[0][3] += g0.x * wv0.w;
            acc[0][0] += g0.y * wv1.x; acc[0][1] += g0.y * wv1.y;
            acc[0][2] += g0.y * wv1.z; acc[0][3] += g0.y * wv1.w;
            acc[1][0] += g1.x * wv0.x; acc[1][1] += g1.x * wv0.y;
            acc[1][2] += g1.x * wv0.z; acc[1][3] += g1.x * wv0.w;
            acc[1][0] += g1.y * wv1.x; acc[1][1] += g1.y * wv1.y;
            acc[1][2] += g1.y * wv1.z; acc[1][3] += g1.y * wv1.w;
        }
    }

    #pragma unroll
    for (int j = 0; j < 4; ++j) {
        outl[mlt * 2][ot * 4 + j]     = acc[0][j];
        outl[mlt * 2 + 1][ot * 4 + j] = acc[1][j];
    }
    __syncthreads();
    // out is (B, Dout, M): out[b][o][m0+mloc]
    #pragma unroll
    for (int i = 0; i < 8; ++i) {
        int fo = i * 256 + t;
        int o = fo >> 4, mloc = fo & 15;
        out[((size_t)b * DOUT_ + o) * M_ + m0 + mloc] = outl[mloc][o];
    }
}

extern "C" void kernel_launch(void* const* d_in, const int* in_sizes, int n_in,
                              void* d_out, int out_size, void* d_ws, size_t ws_size,
                              hipStream_t stream) {
    const float* points_xyz = (const float*)d_in[0];
    const float* features   = (const float*)d_in[1];
    const float* center_xyz = (const float*)d_in[2];
    const int*   nidx       = (const int*)d_in[3];
    const float* kpts       = (const float*)d_in[4];
    const float* weights    = (const float*)d_in[5];
    float* out = (float*)d_out;

    unsigned short* featT = (unsigned short*)d_ws;   // B*(N+1)*Din bf16 = 16.8 MB

    transpose_feats<<<dim3((N_ + 64) / 64, B_), 256, 0, stream>>>(features, featT);
    kpconv_fused<<<dim3(M_ / TM, B_), 256, 0, stream>>>(points_xyz, center_xyz, nidx,
                                                        kpts, weights, featT, out);
}

// Round 3
// 159.450 us; speedup vs baseline: 4.0186x; 4.0186x over previous
//
#include <hip/hip_runtime.h>
#include <hip/hip_bf16.h>
#include <stdint.h>

#define B_    2
#define N_    65536
#define M_    16384
#define K_    32
#define KP_   15
#define DIN_  64
#define DOUT_ 128

typedef __bf16 bf16x8 __attribute__((ext_vector_type(8)));
typedef float  f32x4  __attribute__((ext_vector_type(4)));

__device__ inline float bf2f(unsigned int u) {
    union { unsigned int i; float f; } v; v.i = u << 16; return v.f;
}
__device__ inline unsigned short f2bf(float f) {
    union { float f; unsigned int i; } v; v.f = f;
    unsigned int x = v.i;
    return (unsigned short)((x + 0x7fffu + ((x >> 16) & 1u)) >> 16);  // RNE
}

// ---- K1: features (B, Din, N) f32 -> featT (B, N+1, Din) bf16, row N zeroed ----
__global__ __launch_bounds__(256) void transpose_feats(const float* __restrict__ feats,
                                                       unsigned short* __restrict__ featT) {
    const int b  = blockIdx.y;
    const int n0 = blockIdx.x * 64;
    const int t  = threadIdx.x;
    if (n0 >= N_) {
        if (t < 32)
            ((unsigned int*)(featT + ((size_t)b * (N_ + 1) + N_) * DIN_))[t] = 0u;
        return;
    }
    __shared__ float tile[64][65];
    const int nl = t & 63, dl = t >> 6;
    #pragma unroll
    for (int i = 0; i < 16; ++i) {
        int d = dl + 4 * i;
        tile[d][nl] = feats[((size_t)b * DIN_ + d) * N_ + n0 + nl];
    }
    __syncthreads();
    const int d2 = (t & 31) * 2;
    const int nr = t >> 5;
    #pragma unroll
    for (int i = 0; i < 8; ++i) {
        int n = nr + 8 * i;
        unsigned int u = ((unsigned int)f2bf(tile[d2 + 1][n]) << 16) | f2bf(tile[d2][n]);
        ((unsigned int*)(featT + ((size_t)b * (N_ + 1) + n0 + n) * DIN_))[t & 31] = u;
    }
}

// ---- K2: weights (960,128) f32 -> WT (128,960) bf16 ----
__global__ __launch_bounds__(256) void build_wt(const float* __restrict__ w,
                                                unsigned short* __restrict__ wt) {
    int tid = blockIdx.x * 256 + threadIdx.x;
    if (tid < 960 * 128) {
        int pd = tid >> 7, o = tid & 127;
        wt[o * 960 + pd] = f2bf(w[tid]);
    }
}

// ---- K3: gather + kernel-weights + stage-1 contraction -> weighted [B*M][960] bf16 ----
__global__ __launch_bounds__(256, 3) void gather_weight(
    const float* __restrict__ points_xyz,
    const float* __restrict__ center_xyz,
    const int*   __restrict__ nidx,
    const float* __restrict__ kpts,
    const unsigned short* __restrict__ featT,
    unsigned short* __restrict__ weighted) {

    __shared__ __align__(16) float        wlds[8 * KP_ * 32];   // [m][p][k]  15.4 KB
    __shared__ __align__(16) unsigned int fbuf[8 * 32 * 32];    // [m][k][d2] 32 KB

    const int t  = threadIdx.x;
    const int b  = blockIdx.y;
    const int m0 = blockIdx.x * 8;
    const size_t ibase = ((size_t)b * M_ + m0) * K_;

    // (1) issue all feature gathers into regs (latency hides under w-compute)
    uint4 v[8];
    const int part = t & 7, rbase = t >> 3;
    #pragma unroll
    for (int i = 0; i < 8; ++i) {
        int r = i * 32 + rbase;                   // r = m*32 + k
        int n = nidx[ibase + r];
        v[i] = *(const uint4*)(featT + ((size_t)b * (N_ + 1) + n) * DIN_ + part * 8);
    }

    // (2) kernel-correlation weights: thread = (m = t>>5, k = t&31), all 256 active
    {
        const int m = t >> 5, k = t & 31;
        int n = nidx[ibase + t];
        float px, py, pz;
        if (n < N_) {
            const float* p = points_xyz + ((size_t)b * N_ + n) * 3;
            px = p[0]; py = p[1]; pz = p[2];
        } else {
            px = py = pz = -1000.0f;
        }
        const float* c = center_xyz + ((size_t)b * M_ + m0 + m) * 3;
        float dx = px - c[0], dy = py - c[1], dz = pz - c[2];
        float md = sqrtf(dx * dx + dy * dy + dz * dz);
        #pragma unroll
        for (int s = 16; s > 0; s >>= 1)
            md = fmaxf(md, __shfl_xor(md, s));
        float rsig = 1.0f / (md / 2.1f + 1e-5f);
        #pragma unroll
        for (int p = 0; p < KP_; ++p) {
            float ex = dx - kpts[p * 3 + 0] * md;
            float ey = dy - kpts[p * 3 + 1] * md;
            float ez = dz - kpts[p * 3 + 2] * md;
            float wv = 1.0f - sqrtf(ex * ex + ey * ey + ez * ez) * rsig;
            wlds[(m * KP_ + p) * 32 + k] = wv > 0.0f ? wv : 0.0f;  // k-indexed: conflict-free
        }
    }

    // (3) land gathers in LDS (vmcnt waits here, after ~200 VALU of w-compute)
    #pragma unroll
    for (int i = 0; i < 8; ++i)
        ((uint4*)fbuf)[(i * 32 + rbase) * 8 + part] = v[i];
    __syncthreads();

    // (4) weighted[m][p][d] = sum_k w[m][p][k] * f[m][k][d]; thread = (m, d-pair)
    const int m = t >> 5, d2 = t & 31;
    float acc[KP_][2];
    #pragma unroll
    for (int p = 0; p < KP_; ++p) { acc[p][0] = 0.f; acc[p][1] = 0.f; }

    for (int k4 = 0; k4 < 8; ++k4) {
        float f0[4], f1[4];
        #pragma unroll
        for (int j = 0; j < 4; ++j) {
            unsigned int u = fbuf[(m * 32 + k4 * 4 + j) * 32 + d2];
            f0[j] = bf2f(u & 0xffffu); f1[j] = bf2f(u >> 16);
        }
        #pragma unroll
        for (int p = 0; p < KP_; ++p) {
            float4 w4 = *(const float4*)&wlds[(m * KP_ + p) * 32 + k4 * 4]; // broadcast
            acc[p][0] += w4.x * f0[0]; acc[p][0] += w4.y * f0[1];
            acc[p][0] += w4.z * f0[2]; acc[p][0] += w4.w * f0[3];
            acc[p][1] += w4.x * f1[0]; acc[p][1] += w4.y * f1[1];
            acc[p][1] += w4.z * f1[2]; acc[p][1] += w4.w * f1[3];
        }
    }

    unsigned int* wout = (unsigned int*)weighted + (size_t)(b * M_ + m0 + m) * 480 + d2;
    #pragma unroll
    for (int p = 0; p < KP_; ++p) {
        unsigned int u = ((unsigned int)f2bf(acc[p][1]) << 16) | f2bf(acc[p][0]);
        wout[p * 32] = u;
    }
}

// ---- K4: out[b][o][m] = weighted[bm][960] x WT[o][960]^T  (MFMA bf16) ----
#define GLOAD_LDS16(g, l) __builtin_amdgcn_global_load_lds( \
    (const __attribute__((address_space(1))) unsigned int*)(g), \
    (__attribute__((address_space(3))) unsigned int*)(l), 16, 0, 0)

__global__ __launch_bounds__(512, 2) void gemm_out(
    const unsigned short* __restrict__ weightedG,   // [32768][960] bf16
    const unsigned short* __restrict__ wtG,         // [128][960]  bf16
    float* __restrict__ out) {

    __shared__ __align__(16) char smem[65536];  // A:[2][16KB] @0, B:[2][16KB] @32768

    const int t = threadIdx.x;
    const int w = t >> 6, lane = t & 63;
    const int bm0 = blockIdx.x * 128;
    const int b = bm0 >> 14, m_in_b = bm0 & (M_ - 1);

    const int wr = w >> 2, wc = w & 3;         // 8 waves: 2 (m) x 4 (o)
    const int wm = wr * 64, wo = wc * 32;      // wave tile: 64 m x 32 o

    f32x4 acc[4][2] = {};

    auto stage = [&](int buf, int kt) {
        #pragma unroll
        for (int i = 0; i < 2; ++i) {          // A-tile: 16 chunks of 1024B, 2/wave
            int chunk = w * 2 + i;
            int L = chunk * 1024 + lane * 16;
            int row = L >> 7, col = L & 127;
            int scol = col ^ ((row & 7) << 4);  // inverse-swizzled SOURCE (linear dest)
            const char* src = (const char*)weightedG + (size_t)(bm0 + row) * 1920 + kt * 128 + scol;
            GLOAD_LDS16(src, smem + buf * 16384 + chunk * 1024);
        }
        #pragma unroll
        for (int i = 0; i < 2; ++i) {          // B-tile (WT rows = o)
            int chunk = w * 2 + i;
            int L = chunk * 1024 + lane * 16;
            int row = L >> 7, col = L & 127;
            int scol = col ^ ((row & 7) << 4);
            const char* src = (const char*)wtG + (size_t)row * 1920 + kt * 128 + scol;
            GLOAD_LDS16(src, smem + 32768 + buf * 16384 + chunk * 1024);
        }
    };

    stage(0, 0);
    __syncthreads();

    for (int kt = 0; kt < 15; ++kt) {
        int cur = kt & 1;
        if (kt < 14) stage(cur ^ 1, kt + 1);
        const char* lA = smem + cur * 16384;
        const char* lB = smem + 32768 + cur * 16384;
        #pragma unroll
        for (int ks = 0; ks < 2; ++ks) {
            bf16x8 af[4], bfr[2];
            const int kcol = ks * 64 + (lane >> 4) * 16;   // byte offset of k-slice
            #pragma unroll
            for (int mf = 0; mf < 4; ++mf) {
                int row = wm + mf * 16 + (lane & 15);
                af[mf] = *(const bf16x8*)(lA + row * 128 + (kcol ^ ((row & 7) << 4)));
            }
            #pragma unroll
            for (int of = 0; of < 2; ++of) {
                int row = wo + of * 16 + (lane & 15);
                bfr[of] = *(const bf16x8*)(lB + row * 128 + (kcol ^ ((row & 7) << 4)));
            }
            #pragma unroll
            for (int mf = 0; mf < 4; ++mf)
                #pragma unroll
                for (int of = 0; of < 2; ++of)
                    acc[mf][of] = __builtin_amdgcn_mfma_f32_16x16x32_bf16(
                        af[mf], bfr[of], acc[mf][of], 0, 0, 0);
        }
        __syncthreads();
    }

    // epilogue: stage D[m][o] -> LDS as [o][m] f32 (swizzled), then coalesced store
    #pragma unroll
    for (int mf = 0; mf < 4; ++mf)
        #pragma unroll
        for (int of = 0; of < 2; ++of) {
            int o  = wo + of * 16 + (lane & 15);        // D col
            int mr = wm + mf * 16 + (lane >> 4) * 4;    // D rows (4 consecutive)
            int byte = (o * 512 + mr * 4) ^ ((o & 7) << 4);
            *(f32x4*)(smem + byte) = acc[mf][of];
        }
    __syncthreads();
    #pragma unroll
    for (int pass = 0; pass < 4; ++pass) {
        int o  = pass * 32 + (t >> 4);
        int mc = (t & 15) * 8;
        int b0 = (o * 512 + mc * 4)       ^ ((o & 7) << 4);
        int b1 = (o * 512 + (mc + 4) * 4) ^ ((o & 7) << 4);
        f32x4 v0 = *(const f32x4*)(smem + b0);
        f32x4 v1 = *(const f32x4*)(smem + b1);
        float* dst = out + ((size_t)(b * DOUT_ + o)) * M_ + m_in_b + mc;
        *(f32x4*)dst = v0;
        *(f32x4*)(dst + 4) = v1;
    }
}

extern "C" void kernel_launch(void* const* d_in, const int* in_sizes, int n_in,
                              void* d_out, int out_size, void* d_ws, size_t ws_size,
                              hipStream_t stream) {
    const float* points_xyz = (const float*)d_in[0];
    const float* features   = (const float*)d_in[1];
    const float* center_xyz = (const float*)d_in[2];
    const int*   nidx       = (const int*)d_in[3];
    const float* kpts       = (const float*)d_in[4];
    const float* weights    = (const float*)d_in[5];
    float* out = (float*)d_out;

    unsigned short* featT    = (unsigned short*)d_ws;                         // 16,777,472 B
    unsigned short* wt       = (unsigned short*)((char*)d_ws + 16777472);     //    245,760 B
    unsigned short* weighted = (unsigned short*)((char*)d_ws + 17023232);     // 62,914,560 B

    transpose_feats<<<dim3((N_ + 64) / 64, B_), 256, 0, stream>>>(features, featT);
    build_wt<<<480, 256, 0, stream>>>(weights, wt);
    gather_weight<<<dim3(M_ / 8, B_), 256, 0, stream>>>(points_xyz, center_xyz, nidx,
                                                        kpts, featT, weighted);
    gemm_out<<<B_ * M_ / 128, 512, 0, stream>>>(weighted, wt, out);
}